// Round 9
// baseline (3719.196 us; speedup 1.0000x reference)
//
#include <hip/hip_runtime.h>
#include <stdint.h>
#include <math.h>

// Replicate jax.random threefry2x32 exactly (jax_threefry_partitionable=True).
#define PARTITIONABLE 1

namespace {

constexpr int kB = 4096;
constexpr int kN = 256;
constexpr int kSweeps = 200;
constexpr int kSamp = 8;                 // samples per block
constexpr int kBlocks = kB / kSamp;      // 512 blocks of 256 threads
// block = 4 waves: 2 consumer waves (R=2 rows/thread, all 8 samples) +
// 2 producer waves (next sweep's threefry). Roles rotated by blockIdx so
// co-resident blocks put consumers on different SIMDs.

struct K2 { uint32_t a, b; };

__host__ __device__ constexpr uint32_t crotl(uint32_t x, int d) {
  return (x << d) | (x >> (32 - d));
}

// Threefry-2x32, 20 rounds, exactly as jax/_src/prng.py
__host__ __device__ constexpr K2 ctf(uint32_t k0, uint32_t k1, uint32_t c0, uint32_t c1) {
  uint32_t ks0 = k0, ks1 = k1, ks2 = k0 ^ k1 ^ 0x1BD11BDAu;
  uint32_t x0 = c0 + ks0, x1 = c1 + ks1;
  const int r0[4] = {13, 15, 26, 6};
  const int r1[4] = {17, 29, 16, 24};
  for (int i = 0; i < 4; ++i) { x0 += x1; x1 = crotl(x1, r0[i]); x1 ^= x0; }
  x0 += ks1; x1 += ks2 + 1u;
  for (int i = 0; i < 4; ++i) { x0 += x1; x1 = crotl(x1, r1[i]); x1 ^= x0; }
  x0 += ks2; x1 += ks0 + 2u;
  for (int i = 0; i < 4; ++i) { x0 += x1; x1 = crotl(x1, r0[i]); x1 ^= x0; }
  x0 += ks0; x1 += ks1 + 3u;
  for (int i = 0; i < 4; ++i) { x0 += x1; x1 = crotl(x1, r1[i]); x1 ^= x0; }
  x0 += ks1; x1 += ks2 + 4u;
  for (int i = 0; i < 4; ++i) { x0 += x1; x1 = crotl(x1, r0[i]); x1 ^= x0; }
  x0 += ks2; x1 += ks0 + 5u;
  return K2{x0, x1};
}

struct KeyTable {
  uint32_t s0k[2];               // key for initial spins (k0)
  uint32_t sk[kSweeps][4];       // per sweep: k1a,k1b (accept), k2a,k2b (mask)
};

constexpr KeyTable make_keys() {
  KeyTable t{};
  K2 root{0u, 42u};              // jax.random.key(42) -> (hi=0, lo=42)
#if PARTITIONABLE
  K2 k0 = ctf(root.a, root.b, 0u, 0u);
  K2 kl = ctf(root.a, root.b, 0u, 1u);
#else
  K2 p0 = ctf(root.a, root.b, 0u, 2u);
  K2 p1 = ctf(root.a, root.b, 1u, 3u);
  K2 k0{p0.a, p1.a};
  K2 kl{p0.b, p1.b};
#endif
  t.s0k[0] = k0.a; t.s0k[1] = k0.b;
  K2 k = kl;
  for (int s = 0; s < kSweeps; ++s) {
#if PARTITIONABLE
    K2 kn = ctf(k.a, k.b, 0u, 0u);
    K2 k1 = ctf(k.a, k.b, 0u, 1u);
    K2 k2 = ctf(k.a, k.b, 0u, 2u);
#else
    K2 q0 = ctf(k.a, k.b, 0u, 3u);
    K2 q1 = ctf(k.a, k.b, 1u, 4u);
    K2 q2 = ctf(k.a, k.b, 2u, 5u);
    K2 kn{q0.a, q1.a};
    K2 k1{q2.a, q0.b};
    K2 k2{q1.b, q2.b};
#endif
    t.sk[s][0] = k1.a; t.sk[s][1] = k1.b;
    t.sk[s][2] = k2.a; t.sk[s][3] = k2.b;
    k = kn;
  }
  return t;
}

__constant__ KeyTable g_keys = make_keys();

__device__ __forceinline__ uint32_t rng_bits32(uint32_t ka, uint32_t kb, uint32_t m) {
#if PARTITIONABLE
  K2 r = ctf(ka, kb, 0u, m);
  return r.a ^ r.b;
#else
  constexpr uint32_t H = (uint32_t)(kB * kN / 2);
  uint32_t p = (m < H) ? m : (m - H);
  K2 r = ctf(ka, kb, p, p + H);
  return (m < H) ? r.a : r.b;
#endif
}

__device__ __forceinline__ float bits_to_uniform(uint32_t bits) {
  // jax: bitcast(bits >> 9 | 0x3f800000) - 1.0
  return __uint_as_float((bits >> 9) | 0x3f800000u) - 1.0f;
}

// prep: build betas and the permuted coupling matrix Jp.
// Jp layout: float idx = ((cw*32 + c)*64 + l)*16 + r*8 + f
//   value = Jsym[cw*128 + 2l + r][c*8 + f]
// so consumer-wave cw, lane l reads 64B contiguous per chunk c (coalesced).
__global__ void prep_kernel(const float* __restrict__ gamma,
                            float* __restrict__ jp,
                            float* __restrict__ betas) {
  int e = blockIdx.x * blockDim.x + threadIdx.x;   // 0..65535
  int i = e / kN, j = e % kN;
  float v = 0.0f;
  if (i < j) v = gamma[i * kN + j];
  else if (i > j) v = gamma[j * kN + i];
  int cw = i >> 7, l = (i & 127) >> 1, r = i & 1, c = j >> 3, f = j & 7;
  jp[((cw * 32 + c) * 64 + l) * 16 + r * 8 + f] = v;
  if (e < kSweeps) {
    double l0 = log(0.1), l1 = log(5.0);
    betas[e] = (float)exp(l0 + (l1 - l0) * (double)e / (double)(kSweeps - 1));
  }
}

// One VALU op per element: f32 fma with the f16 spin operand converted in-op.
// Conversion of +-1.0h to f32 is exact, then fp32 fma -> bit-identical to
// fmaf(+-1.0f, J, acc). op_sel picks lo/hi half of the packed u32.
#define FMIX_LO(a, w, j)                                                      \
  asm("v_fma_mix_f32 %0, %1, %2, %0 op_sel:[0,0,0] op_sel_hi:[1,0,0]"         \
      : "+v"(a) : "v"(w), "v"(j))
#define FMIX_HI(a, w, j)                                                      \
  asm("v_fma_mix_f32 %0, %1, %2, %0 op_sel:[1,0,0] op_sel_hi:[1,0,0]"         \
      : "+v"(a) : "v"(w), "v"(j))

__global__ __launch_bounds__(256) void anneal_kernel(
    const float* __restrict__ thetas, const float* __restrict__ jp,
    const float* __restrict__ betas, float* __restrict__ out) {
  // fp16 spins (+1.0h=0x3C00, -1.0h=0xBC00), [buf][g][row], dbuf: 8 KiB
  __shared__ __align__(16) unsigned short sh_h[2][kSamp][kN];
  // packed randoms w = ((b1>>9)<<1)|(b2>>31), one u32/site, dbuf: 16 KiB
  __shared__ __align__(16) uint32_t sh_rand[2][kSamp * kN];
  __shared__ float sh_red[kSamp][4];

  const int tid = threadIdx.x;
  const int lane = tid & 63;
  const int wvid = tid >> 6;                     // physical wave 0..3
  const int rot = (blockIdx.x ^ (blockIdx.x >> 8)) & 1;
  const int wl = wvid ^ (rot << 1);              // logical: 0,1=C; 2,3=P
  const bool consumer = (wl < 2);
  const int b0 = blockIdx.x * kSamp;             // first sample of block

  int cur = 0;

  if (consumer) {
    const int cw = wl;                           // consumer wave 0/1
    const int row0 = cw * 128 + 2 * lane;        // rows row0, row0+1

    // th_[2g+r] = theta of (sample g, row r); sreg[g] = fp16 spin pair
    float th_[16];
    uint32_t sreg[kSamp];
#pragma unroll
    for (int g = 0; g < kSamp; ++g) {
      float2 t2 = *(const float2*)&thetas[(b0 + g) * kN + row0];
      th_[2 * g] = t2.x; th_[2 * g + 1] = t2.y;
    }
    // s0 = where(bernoulli(k0, 0.5), 1, -1) ; bernoulli = uniform < 0.5
#pragma unroll
    for (int g = 0; g < kSamp; ++g) {
      uint32_t m0 = (uint32_t)((b0 + g) * kN + row0);
      float u0 = bits_to_uniform(rng_bits32(g_keys.s0k[0], g_keys.s0k[1], m0));
      float u1 = bits_to_uniform(rng_bits32(g_keys.s0k[0], g_keys.s0k[1], m0 + 1));
      uint32_t pk = ((u0 < 0.5f) ? 0x3C00u : 0xBC00u) |
                    (((u1 < 0.5f) ? 0x3C00u : 0xBC00u) << 16);
      sreg[g] = pk;
      *(uint32_t*)&sh_h[0][g][row0] = pk;        // FIXED: was [2*lane]
    }
    __syncthreads();

    // this thread's coalesced Jp slice: chunk c at jpt[c*256 + 0..3]
    const float4* __restrict__ jpt =
        (const float4*)jp + (size_t)cw * 8192 + (size_t)lane * 4;

#define LDSPIN(g, c) (*(const uint4*)&sh_h[cur][g][(c) * 8])
    // consume chunk (8 j) for 8 samples x 2 rows: 128 fma_mix, j ascending
#define CONSUME2(W, Q0, Q1, Q2, Q3)                                           \
  _Pragma("unroll")                                                           \
  for (int g = 0; g < kSamp; ++g) {                                           \
    FMIX_LO(acc[2*g], W[g].x, Q0.x); FMIX_HI(acc[2*g], W[g].x, Q0.y);         \
    FMIX_LO(acc[2*g], W[g].y, Q0.z); FMIX_HI(acc[2*g], W[g].y, Q0.w);         \
    FMIX_LO(acc[2*g], W[g].z, Q1.x); FMIX_HI(acc[2*g], W[g].z, Q1.y);         \
    FMIX_LO(acc[2*g], W[g].w, Q1.z); FMIX_HI(acc[2*g], W[g].w, Q1.w);         \
    FMIX_LO(acc[2*g+1], W[g].x, Q2.x); FMIX_HI(acc[2*g+1], W[g].x, Q2.y);     \
    FMIX_LO(acc[2*g+1], W[g].y, Q2.z); FMIX_HI(acc[2*g+1], W[g].y, Q2.w);     \
    FMIX_LO(acc[2*g+1], W[g].z, Q3.x); FMIX_HI(acc[2*g+1], W[g].z, Q3.y);     \
    FMIX_LO(acc[2*g+1], W[g].w, Q3.z); FMIX_HI(acc[2*g+1], W[g].w, Q3.w);     \
  }
    // matvec body as a statement macro so the A/B pipeline shape is fixed
#define MATVEC(acc)                                                           \
  {                                                                           \
    uint4 A[kSamp], Bw[kSamp];                                                \
    float4 a0, a1, a2, a3, b0_, b1_, b2_, b3_;                                \
    _Pragma("unroll")                                                         \
    for (int g = 0; g < kSamp; ++g) A[g] = LDSPIN(g, 0);                      \
    a0 = jpt[0]; a1 = jpt[1]; a2 = jpt[2]; a3 = jpt[3];                       \
    _Pragma("unroll 1")                                                       \
    for (int k = 0; k < 15; ++k) {                                            \
      const int c = 2 * k;                                                    \
      _Pragma("unroll")                                                       \
      for (int g = 0; g < kSamp; ++g) Bw[g] = LDSPIN(g, c + 1);               \
      b0_ = jpt[(c + 1) * 256 + 0]; b1_ = jpt[(c + 1) * 256 + 1];             \
      b2_ = jpt[(c + 1) * 256 + 2]; b3_ = jpt[(c + 1) * 256 + 3];             \
      CONSUME2(A, a0, a1, a2, a3)                                             \
      _Pragma("unroll")                                                       \
      for (int g = 0; g < kSamp; ++g) A[g] = LDSPIN(g, c + 2);                \
      a0 = jpt[(c + 2) * 256 + 0]; a1 = jpt[(c + 2) * 256 + 1];               \
      a2 = jpt[(c + 2) * 256 + 2]; a3 = jpt[(c + 2) * 256 + 3];               \
      CONSUME2(Bw, b0_, b1_, b2_, b3_)                                        \
    }                                                                         \
    _Pragma("unroll")                                                         \
    for (int g = 0; g < kSamp; ++g) Bw[g] = LDSPIN(g, 31);                    \
    b0_ = jpt[31 * 256 + 0]; b1_ = jpt[31 * 256 + 1];                         \
    b2_ = jpt[31 * 256 + 2]; b3_ = jpt[31 * 256 + 3];                         \
    CONSUME2(A, a0, a1, a2, a3)                                               \
    CONSUME2(Bw, b0_, b1_, b2_, b3_)                                          \
  }

#pragma unroll 1
    for (int t = 0; t < kSweeps; ++t) {
      const float beta = betas[t];
      // randoms for this sweep (produced last sweep / prologue): 2 sites/g
      uint2 wp[kSamp];
      {
        const uint32_t* __restrict__ rb = &sh_rand[t & 1][cw * 128 + 2 * lane];
#pragma unroll
        for (int g = 0; g < kSamp; ++g)
          wp[g] = *(const uint2*)&rb[g * kN];
      }

      float acc[16];
#pragma unroll
      for (int x = 0; x < 16; ++x) acc[x] = 0.0f;
      MATVEC(acc)

#pragma unroll
      for (int g = 0; g < kSamp; ++g) {
        uint32_t pk = sreg[g];
        float s0f = __uint_as_float(0x3F800000u | ((pk << 16) & 0x80000000u));
        float s1f = __uint_as_float(0x3F800000u | (pk & 0x80000000u));
        float l0 = th_[2 * g] + acc[2 * g];
        float l1 = th_[2 * g + 1] + acc[2 * g + 1];
        float d0 = -2.0f * s0f * l0;       // exact: (-2*s) power of two
        float d1 = -2.0f * s1f * l1;
        float p0 = expf(-beta * d0);
        float p1 = expf(-beta * d1);
        float u0 = __uint_as_float((wp[g].x >> 1) | 0x3f800000u) - 1.0f;
        float u1 = __uint_as_float((wp[g].y >> 1) | 0x3f800000u) - 1.0f;
        uint32_t msk = 0u;
        if ((u0 < p0) && ((wp[g].x & 1u) == 0u)) msk |= 0x8000u;
        if ((u1 < p1) && ((wp[g].y & 1u) == 0u)) msk |= 0x80000000u;
        pk ^= msk;                          // flip = fp16 sign flip
        sreg[g] = pk;
        *(uint32_t*)&sh_h[cur ^ 1][g][row0] = pk;   // FIXED: was [2*lane]
      }
      __syncthreads();
      cur ^= 1;
    }

    // E_b = sum_i s_i*theta_i + 0.5 * sum_i s_i * (Jsym s)_i
    {
      float acc[16];
#pragma unroll
      for (int x = 0; x < 16; ++x) acc[x] = 0.0f;
      MATVEC(acc)

#pragma unroll
      for (int g = 0; g < kSamp; ++g) {
        uint32_t pk = sreg[g];
        float s0f = __uint_as_float(0x3F800000u | ((pk << 16) & 0x80000000u));
        float s1f = __uint_as_float(0x3F800000u | (pk & 0x80000000u));
        // identical expression to previous rounds: v = s*th + 0.5f*(s*acc)
        float x0 = s0f * th_[2 * g] + 0.5f * (s0f * acc[2 * g]);
        float x1 = s1f * th_[2 * g + 1] + 0.5f * (s1f * acc[2 * g + 1]);
        // slot-split tree == old 64-lane shfl tree (offsets 32,16,8,4,2,1):
        // here offsets 16,8,4,2,1 on both row-slots, then slot add.
#pragma unroll
        for (int off = 16; off > 0; off >>= 1) {
          x0 += __shfl_down(x0, off);
          x1 += __shfl_down(x1, off);
        }
        float v = x0 + x1;
        if (lane == 0)  sh_red[g][2 * cw + 0] = v;   // rows [cw*128, +64)
        if (lane == 32) sh_red[g][2 * cw + 1] = v;   // rows [cw*128+64, +64)
      }
    }
  } else {
    // ---------------- producer waves ----------------
    const int p = (wl - 2) * 64 + lane;            // 0..127, 16 sites each
    {
      const uint32_t k1a = g_keys.sk[0][0], k1b = g_keys.sk[0][1];
      const uint32_t k2a = g_keys.sk[0][2], k2b = g_keys.sk[0][3];
      const uint32_t mb = (uint32_t)(b0 * kN + p * 16);
#pragma unroll 4
      for (int q = 0; q < 16; ++q) {
        uint32_t b1 = rng_bits32(k1a, k1b, mb + q);
        uint32_t b2 = rng_bits32(k2a, k2b, mb + q);
        sh_rand[0][p * 16 + q] = ((b1 >> 9) << 1) | (b2 >> 31);
      }
    }
    __syncthreads();

#pragma unroll 1
    for (int t = 0; t < kSweeps; ++t) {
      if (t + 1 < kSweeps) {
        const uint32_t k1a = g_keys.sk[t + 1][0], k1b = g_keys.sk[t + 1][1];
        const uint32_t k2a = g_keys.sk[t + 1][2], k2b = g_keys.sk[t + 1][3];
        const uint32_t mb = (uint32_t)(b0 * kN + p * 16);
        uint32_t wv[16];
#pragma unroll 4
        for (int q = 0; q < 16; ++q) {
          uint32_t b1 = rng_bits32(k1a, k1b, mb + q);
          uint32_t b2 = rng_bits32(k2a, k2b, mb + q);
          wv[q] = ((b1 >> 9) << 1) | (b2 >> 31);
        }
        uint32_t* dst = &sh_rand[(t + 1) & 1][p * 16];
#pragma unroll
        for (int q = 0; q < 4; ++q) {
          uint4 v; v.x = wv[4*q]; v.y = wv[4*q+1]; v.z = wv[4*q+2]; v.w = wv[4*q+3];
          *(uint4*)(dst + 4 * q) = v;
        }
      }
      __syncthreads();
    }
  }

  __syncthreads();
  if (tid < kSamp) {
    out[b0 + tid] =
        sh_red[tid][0] + sh_red[tid][1] + sh_red[tid][2] + sh_red[tid][3];
  }
}

}  // namespace

extern "C" void kernel_launch(void* const* d_in, const int* in_sizes, int n_in,
                              void* d_out, int out_size, void* d_ws, size_t ws_size,
                              hipStream_t stream) {
  const float* thetas = (const float*)d_in[0];   // [4096, 256]
  const float* gamma  = (const float*)d_in[1];   // [256, 256]
  float* jp    = (float*)d_ws;                              // 256 KiB permuted J
  float* betas = (float*)((char*)d_ws + kN * kN * sizeof(float));

  hipLaunchKernelGGL(prep_kernel, dim3(kN), dim3(kN), 0, stream, gamma, jp, betas);
  hipLaunchKernelGGL(anneal_kernel, dim3(kBlocks), dim3(256), 0, stream,
                     thetas, jp, betas, (float*)d_out);
}

// Round 10
// 2218.023 us; speedup vs baseline: 1.6768x; 1.6768x over previous
//
#include <hip/hip_runtime.h>
#include <stdint.h>
#include <math.h>

// Replicate jax.random threefry2x32 exactly (jax_threefry_partitionable=True).
#define PARTITIONABLE 1

namespace {

constexpr int kB = 4096;
constexpr int kN = 256;
constexpr int kSweeps = 200;
constexpr int kSamp = 16;                // samples per block (two octets)
constexpr int kBlocks = kB / kSamp;      // 256 blocks of 512 threads -> 1/CU
// block = 8 waves: waves 0-3 consumers (wave cw: sample-octet cw&1,
// row-half cw>>1, 2 rows/thread), waves 4-7 producers (next sweep threefry).
// Wave w -> SIMD w%4 gives every SIMD exactly 1 consumer + 1 producer.

struct K2 { uint32_t a, b; };

__host__ __device__ constexpr uint32_t crotl(uint32_t x, int d) {
  return (x << d) | (x >> (32 - d));
}

// Threefry-2x32, 20 rounds, exactly as jax/_src/prng.py
__host__ __device__ constexpr K2 ctf(uint32_t k0, uint32_t k1, uint32_t c0, uint32_t c1) {
  uint32_t ks0 = k0, ks1 = k1, ks2 = k0 ^ k1 ^ 0x1BD11BDAu;
  uint32_t x0 = c0 + ks0, x1 = c1 + ks1;
  const int r0[4] = {13, 15, 26, 6};
  const int r1[4] = {17, 29, 16, 24};
  for (int i = 0; i < 4; ++i) { x0 += x1; x1 = crotl(x1, r0[i]); x1 ^= x0; }
  x0 += ks1; x1 += ks2 + 1u;
  for (int i = 0; i < 4; ++i) { x0 += x1; x1 = crotl(x1, r1[i]); x1 ^= x0; }
  x0 += ks2; x1 += ks0 + 2u;
  for (int i = 0; i < 4; ++i) { x0 += x1; x1 = crotl(x1, r0[i]); x1 ^= x0; }
  x0 += ks0; x1 += ks1 + 3u;
  for (int i = 0; i < 4; ++i) { x0 += x1; x1 = crotl(x1, r1[i]); x1 ^= x0; }
  x0 += ks1; x1 += ks2 + 4u;
  for (int i = 0; i < 4; ++i) { x0 += x1; x1 = crotl(x1, r0[i]); x1 ^= x0; }
  x0 += ks2; x1 += ks0 + 5u;
  return K2{x0, x1};
}

struct KeyTable {
  uint32_t s0k[2];               // key for initial spins (k0)
  uint32_t sk[kSweeps][4];       // per sweep: k1a,k1b (accept), k2a,k2b (mask)
};

constexpr KeyTable make_keys() {
  KeyTable t{};
  K2 root{0u, 42u};              // jax.random.key(42) -> (hi=0, lo=42)
#if PARTITIONABLE
  K2 k0 = ctf(root.a, root.b, 0u, 0u);
  K2 kl = ctf(root.a, root.b, 0u, 1u);
#else
  K2 p0 = ctf(root.a, root.b, 0u, 2u);
  K2 p1 = ctf(root.a, root.b, 1u, 3u);
  K2 k0{p0.a, p1.a};
  K2 kl{p0.b, p1.b};
#endif
  t.s0k[0] = k0.a; t.s0k[1] = k0.b;
  K2 k = kl;
  for (int s = 0; s < kSweeps; ++s) {
#if PARTITIONABLE
    K2 kn = ctf(k.a, k.b, 0u, 0u);
    K2 k1 = ctf(k.a, k.b, 0u, 1u);
    K2 k2 = ctf(k.a, k.b, 0u, 2u);
#else
    K2 q0 = ctf(k.a, k.b, 0u, 3u);
    K2 q1 = ctf(k.a, k.b, 1u, 4u);
    K2 q2 = ctf(k.a, k.b, 2u, 5u);
    K2 kn{q0.a, q1.a};
    K2 k1{q2.a, q0.b};
    K2 k2{q1.b, q2.b};
#endif
    t.sk[s][0] = k1.a; t.sk[s][1] = k1.b;
    t.sk[s][2] = k2.a; t.sk[s][3] = k2.b;
    k = kn;
  }
  return t;
}

__constant__ KeyTable g_keys = make_keys();

__device__ __forceinline__ uint32_t rng_bits32(uint32_t ka, uint32_t kb, uint32_t m) {
#if PARTITIONABLE
  K2 r = ctf(ka, kb, 0u, m);
  return r.a ^ r.b;
#else
  constexpr uint32_t H = (uint32_t)(kB * kN / 2);
  uint32_t p = (m < H) ? m : (m - H);
  K2 r = ctf(ka, kb, p, p + H);
  return (m < H) ? r.a : r.b;
#endif
}

__device__ __forceinline__ float bits_to_uniform(uint32_t bits) {
  // jax: bitcast(bits >> 9 | 0x3f800000) - 1.0
  return __uint_as_float((bits >> 9) | 0x3f800000u) - 1.0f;
}

// prep: build betas and the permuted coupling matrix Jp.
// Jp layout: float idx = ((rh*32 + c)*64 + l)*16 + r*8 + f
//   value = Jsym[rh*128 + 2l + r][c*8 + f]
// so row-half rh, lane l reads 64B contiguous per chunk c (coalesced).
__global__ void prep_kernel(const float* __restrict__ gamma,
                            float* __restrict__ jp,
                            float* __restrict__ betas) {
  int e = blockIdx.x * blockDim.x + threadIdx.x;   // 0..65535
  int i = e / kN, j = e % kN;
  float v = 0.0f;
  if (i < j) v = gamma[i * kN + j];
  else if (i > j) v = gamma[j * kN + i];
  int rh = i >> 7, l = (i & 127) >> 1, r = i & 1, c = j >> 3, f = j & 7;
  jp[((rh * 32 + c) * 64 + l) * 16 + r * 8 + f] = v;
  if (e < kSweeps) {
    double l0 = log(0.1), l1 = log(5.0);
    betas[e] = (float)exp(l0 + (l1 - l0) * (double)e / (double)(kSweeps - 1));
  }
}

// One VALU op per element: f32 fma with the f16 spin operand converted in-op.
// Conversion of +-1.0h to f32 is exact, then fp32 fma -> bit-identical to
// fmaf(+-1.0f, J, acc). op_sel picks lo/hi half of the packed u32.
#define FMIX_LO(a, w, j)                                                      \
  asm("v_fma_mix_f32 %0, %1, %2, %0 op_sel:[0,0,0] op_sel_hi:[1,0,0]"         \
      : "+v"(a) : "v"(w), "v"(j))
#define FMIX_HI(a, w, j)                                                      \
  asm("v_fma_mix_f32 %0, %1, %2, %0 op_sel:[1,0,0] op_sel_hi:[1,0,0]"         \
      : "+v"(a) : "v"(w), "v"(j))

__global__ __launch_bounds__(512) void anneal_kernel(
    const float* __restrict__ thetas, const float* __restrict__ jp,
    const float* __restrict__ betas, float* __restrict__ out) {
  // fp16 spins (+1.0h=0x3C00, -1.0h=0xBC00), [buf][g][row], dbuf: 16 KiB
  __shared__ __align__(16) unsigned short sh_h[2][kSamp][kN];
  // packed randoms w = ((b1>>9)<<1)|(b2>>31), one u32/site, dbuf: 32 KiB
  __shared__ __align__(16) uint32_t sh_rand[2][kSamp * kN];
  __shared__ float sh_red[kSamp][4];

  const int tid = threadIdx.x;
  const int lane = tid & 63;
  const int wvid = tid >> 6;                     // wave 0..7 -> SIMD wvid%4
  const bool consumer = (wvid < 4);
  const int b0 = blockIdx.x * kSamp;             // first sample of block

  int cur = 0;

  if (consumer) {
    const int cw = wvid;                         // consumer wave 0..3
    const int oct = cw & 1;                      // sample octet 0/1
    const int rh = cw >> 1;                      // row half 0/1
    const int gbase = oct * 8;                   // first sample of octet
    const int row0 = rh * 128 + 2 * lane;        // rows row0, row0+1

    // th_[2g+r] = theta of (sample gbase+g, row r); sreg[g] = fp16 spin pair
    float th_[16];
    uint32_t sreg[8];
#pragma unroll
    for (int g = 0; g < 8; ++g) {
      float2 t2 = *(const float2*)&thetas[(b0 + gbase + g) * kN + row0];
      th_[2 * g] = t2.x; th_[2 * g + 1] = t2.y;
    }
    // s0 = where(bernoulli(k0, 0.5), 1, -1) ; bernoulli = uniform < 0.5
#pragma unroll
    for (int g = 0; g < 8; ++g) {
      uint32_t m0 = (uint32_t)((b0 + gbase + g) * kN + row0);
      float u0 = bits_to_uniform(rng_bits32(g_keys.s0k[0], g_keys.s0k[1], m0));
      float u1 = bits_to_uniform(rng_bits32(g_keys.s0k[0], g_keys.s0k[1], m0 + 1));
      uint32_t pk = ((u0 < 0.5f) ? 0x3C00u : 0xBC00u) |
                    (((u1 < 0.5f) ? 0x3C00u : 0xBC00u) << 16);
      sreg[g] = pk;
      *(uint32_t*)&sh_h[0][gbase + g][row0] = pk;
    }
    __syncthreads();

    // this thread's coalesced Jp slice: chunk c at jpt[c*256 + 0..3]
    const float4* __restrict__ jpt =
        (const float4*)jp + (size_t)rh * 8192 + (size_t)lane * 4;

#define LDSPIN(g, c) (*(const uint4*)&sh_h[cur][gbase + (g)][(c) * 8])
    // consume chunk (8 j) for 8 samples x 2 rows: 128 fma_mix, j ascending
#define CONSUME2(W, Q0, Q1, Q2, Q3)                                           \
  _Pragma("unroll")                                                           \
  for (int g = 0; g < 8; ++g) {                                               \
    FMIX_LO(acc[2*g], W[g].x, Q0.x); FMIX_HI(acc[2*g], W[g].x, Q0.y);         \
    FMIX_LO(acc[2*g], W[g].y, Q0.z); FMIX_HI(acc[2*g], W[g].y, Q0.w);         \
    FMIX_LO(acc[2*g], W[g].z, Q1.x); FMIX_HI(acc[2*g], W[g].z, Q1.y);         \
    FMIX_LO(acc[2*g], W[g].w, Q1.z); FMIX_HI(acc[2*g], W[g].w, Q1.w);         \
    FMIX_LO(acc[2*g+1], W[g].x, Q2.x); FMIX_HI(acc[2*g+1], W[g].x, Q2.y);     \
    FMIX_LO(acc[2*g+1], W[g].y, Q2.z); FMIX_HI(acc[2*g+1], W[g].y, Q2.w);     \
    FMIX_LO(acc[2*g+1], W[g].z, Q3.x); FMIX_HI(acc[2*g+1], W[g].z, Q3.y);     \
    FMIX_LO(acc[2*g+1], W[g].w, Q3.z); FMIX_HI(acc[2*g+1], W[g].w, Q3.w);     \
  }
    // matvec body as a statement macro so the A/B pipeline shape is fixed
#define MATVEC(acc)                                                           \
  {                                                                           \
    uint4 A[8], Bw[8];                                                        \
    float4 a0, a1, a2, a3, b0_, b1_, b2_, b3_;                                \
    _Pragma("unroll")                                                         \
    for (int g = 0; g < 8; ++g) A[g] = LDSPIN(g, 0);                          \
    a0 = jpt[0]; a1 = jpt[1]; a2 = jpt[2]; a3 = jpt[3];                       \
    _Pragma("unroll 1")                                                       \
    for (int k = 0; k < 15; ++k) {                                            \
      const int c = 2 * k;                                                    \
      _Pragma("unroll")                                                       \
      for (int g = 0; g < 8; ++g) Bw[g] = LDSPIN(g, c + 1);                   \
      b0_ = jpt[(c + 1) * 256 + 0]; b1_ = jpt[(c + 1) * 256 + 1];             \
      b2_ = jpt[(c + 1) * 256 + 2]; b3_ = jpt[(c + 1) * 256 + 3];             \
      CONSUME2(A, a0, a1, a2, a3)                                             \
      _Pragma("unroll")                                                       \
      for (int g = 0; g < 8; ++g) A[g] = LDSPIN(g, c + 2);                    \
      a0 = jpt[(c + 2) * 256 + 0]; a1 = jpt[(c + 2) * 256 + 1];               \
      a2 = jpt[(c + 2) * 256 + 2]; a3 = jpt[(c + 2) * 256 + 3];               \
      CONSUME2(Bw, b0_, b1_, b2_, b3_)                                        \
    }                                                                         \
    _Pragma("unroll")                                                         \
    for (int g = 0; g < 8; ++g) Bw[g] = LDSPIN(g, 31);                        \
    b0_ = jpt[31 * 256 + 0]; b1_ = jpt[31 * 256 + 1];                         \
    b2_ = jpt[31 * 256 + 2]; b3_ = jpt[31 * 256 + 3];                         \
    CONSUME2(A, a0, a1, a2, a3)                                               \
    CONSUME2(Bw, b0_, b1_, b2_, b3_)                                          \
  }

#pragma unroll 1
    for (int t = 0; t < kSweeps; ++t) {
      const float beta = betas[t];
      // randoms for this sweep (produced last sweep / prologue): 2 sites/g
      uint2 wp[8];
      {
        const uint32_t* __restrict__ rb =
            &sh_rand[t & 1][gbase * kN + rh * 128 + 2 * lane];
#pragma unroll
        for (int g = 0; g < 8; ++g)
          wp[g] = *(const uint2*)&rb[g * kN];
      }

      float acc[16];
#pragma unroll
      for (int x = 0; x < 16; ++x) acc[x] = 0.0f;
      MATVEC(acc)

#pragma unroll
      for (int g = 0; g < 8; ++g) {
        uint32_t pk = sreg[g];
        float s0f = __uint_as_float(0x3F800000u | ((pk << 16) & 0x80000000u));
        float s1f = __uint_as_float(0x3F800000u | (pk & 0x80000000u));
        float l0 = th_[2 * g] + acc[2 * g];
        float l1 = th_[2 * g + 1] + acc[2 * g + 1];
        float d0 = -2.0f * s0f * l0;       // exact: (-2*s) power of two
        float d1 = -2.0f * s1f * l1;
        float p0 = expf(-beta * d0);
        float p1 = expf(-beta * d1);
        float u0 = __uint_as_float((wp[g].x >> 1) | 0x3f800000u) - 1.0f;
        float u1 = __uint_as_float((wp[g].y >> 1) | 0x3f800000u) - 1.0f;
        uint32_t msk = 0u;
        if ((u0 < p0) && ((wp[g].x & 1u) == 0u)) msk |= 0x8000u;
        if ((u1 < p1) && ((wp[g].y & 1u) == 0u)) msk |= 0x80000000u;
        pk ^= msk;                          // flip = fp16 sign flip
        sreg[g] = pk;
        *(uint32_t*)&sh_h[cur ^ 1][gbase + g][row0] = pk;
      }
      __syncthreads();
      cur ^= 1;
    }

    // E_b = sum_i s_i*theta_i + 0.5 * sum_i s_i * (Jsym s)_i
    {
      float acc[16];
#pragma unroll
      for (int x = 0; x < 16; ++x) acc[x] = 0.0f;
      MATVEC(acc)

#pragma unroll
      for (int g = 0; g < 8; ++g) {
        uint32_t pk = sreg[g];
        float s0f = __uint_as_float(0x3F800000u | ((pk << 16) & 0x80000000u));
        float s1f = __uint_as_float(0x3F800000u | (pk & 0x80000000u));
        // identical expression to previous rounds: v = s*th + 0.5f*(s*acc)
        float x0 = s0f * th_[2 * g] + 0.5f * (s0f * acc[2 * g]);
        float x1 = s1f * th_[2 * g + 1] + 0.5f * (s1f * acc[2 * g + 1]);
        // slot-split tree == old 64-lane shfl tree (offsets 32,16,8,4,2,1):
        // here offsets 16,8,4,2,1 on both row-slots, then slot add.
#pragma unroll
        for (int off = 16; off > 0; off >>= 1) {
          x0 += __shfl_down(x0, off);
          x1 += __shfl_down(x1, off);
        }
        float v = x0 + x1;
        if (lane == 0)  sh_red[gbase + g][2 * rh + 0] = v;  // rows [rh*128,+64)
        if (lane == 32) sh_red[gbase + g][2 * rh + 1] = v;  // rows [rh*128+64,+64)
      }
    }
  } else {
    // ---------------- producer waves (4..7) ----------------
    const int p = (wvid - 4) * 64 + lane;          // 0..255, 16 sites each
    {
      const uint32_t k1a = g_keys.sk[0][0], k1b = g_keys.sk[0][1];
      const uint32_t k2a = g_keys.sk[0][2], k2b = g_keys.sk[0][3];
      const uint32_t mb = (uint32_t)(b0 * kN + p * 16);
#pragma unroll 4
      for (int q = 0; q < 16; ++q) {
        uint32_t b1 = rng_bits32(k1a, k1b, mb + q);
        uint32_t b2 = rng_bits32(k2a, k2b, mb + q);
        sh_rand[0][p * 16 + q] = ((b1 >> 9) << 1) | (b2 >> 31);
      }
    }
    __syncthreads();

#pragma unroll 1
    for (int t = 0; t < kSweeps; ++t) {
      if (t + 1 < kSweeps) {
        const uint32_t k1a = g_keys.sk[t + 1][0], k1b = g_keys.sk[t + 1][1];
        const uint32_t k2a = g_keys.sk[t + 1][2], k2b = g_keys.sk[t + 1][3];
        const uint32_t mb = (uint32_t)(b0 * kN + p * 16);
        uint32_t wv[16];
#pragma unroll 4
        for (int q = 0; q < 16; ++q) {
          uint32_t b1 = rng_bits32(k1a, k1b, mb + q);
          uint32_t b2 = rng_bits32(k2a, k2b, mb + q);
          wv[q] = ((b1 >> 9) << 1) | (b2 >> 31);
        }
        uint32_t* dst = &sh_rand[(t + 1) & 1][p * 16];
#pragma unroll
        for (int q = 0; q < 4; ++q) {
          uint4 v; v.x = wv[4*q]; v.y = wv[4*q+1]; v.z = wv[4*q+2]; v.w = wv[4*q+3];
          *(uint4*)(dst + 4 * q) = v;
        }
      }
      __syncthreads();
    }
  }

  __syncthreads();
  if (tid < kSamp) {
    out[b0 + tid] =
        sh_red[tid][0] + sh_red[tid][1] + sh_red[tid][2] + sh_red[tid][3];
  }
}

}  // namespace

extern "C" void kernel_launch(void* const* d_in, const int* in_sizes, int n_in,
                              void* d_out, int out_size, void* d_ws, size_t ws_size,
                              hipStream_t stream) {
  const float* thetas = (const float*)d_in[0];   // [4096, 256]
  const float* gamma  = (const float*)d_in[1];   // [256, 256]
  float* jp    = (float*)d_ws;                              // 256 KiB permuted J
  float* betas = (float*)((char*)d_ws + kN * kN * sizeof(float));

  hipLaunchKernelGGL(prep_kernel, dim3(kN), dim3(kN), 0, stream, gamma, jp, betas);
  hipLaunchKernelGGL(anneal_kernel, dim3(kBlocks), dim3(512), 0, stream,
                     thetas, jp, betas, (float*)d_out);
}